// Round 6
// baseline (207.673 us; speedup 1.0000x reference)
//
#include <hip/hip_runtime.h>
#include <hip/hip_fp16.h>

#define D 64
#define BSH2 8                   // 256 nodes per coarse bucket
#define NPB 256                  // nodes per bucket
#define NB2_MAX 512              // max buckets (N <= 131072)
#define PCHUNK 4096              // edges per partition block
#define CAPP 6144                // packed region capacity per bucket (incl. pad, x16)
#define CAP2 4096                // csr region capacity per bucket (real edges)

// clang-native vector types: __builtin_nontemporal_store requires ext_vector_type,
// NOT the HIP_vector_type classes (uint4/float4) -- those fail to compile.
typedef unsigned int uint32x4 __attribute__((ext_vector_type(4)));
typedef float f32x4 __attribute__((ext_vector_type(4)));

// ---------------- utility ----------------

__global__ void zero_f32(float* __restrict__ p, long n) {
    long i = (long)blockIdx.x * blockDim.x + threadIdx.x;
    long stride = (long)gridDim.x * blockDim.x;
    for (; i < n; i += stride) p[i] = 0.0f;
}

__global__ void init_cursors(int* __restrict__ gcur, int NB2) {
    int i = blockIdx.x * blockDim.x + threadIdx.x;
    if (i < NB2) gcur[i << 4] = i * CAPP;
}

// ---------------- build: single-pass partition (1024 threads) ----------------
__global__ __launch_bounds__(1024) void partition_direct(const int* __restrict__ src,
                                                         const int* __restrict__ dst,
                                                         int* __restrict__ gcur,  // stride 16
                                                         int* __restrict__ packed,
                                                         int E, int NB2) {
    __shared__ int staged[PCHUNK];     // 16 KB sorted chunk
    __shared__ int lhist[NB2_MAX];
    __shared__ int lbase[NB2_MAX];
    __shared__ int lcur[NB2_MAX];
    __shared__ int gbase[NB2_MAX];
    int tid = threadIdx.x;
    int c0 = blockIdx.x * PCHUNK;
    int c1 = c0 + PCHUNK; if (c1 > E) c1 = E;

    if (tid < NB2_MAX) lhist[tid] = 0;
    __syncthreads();

    // 1: histogram
    for (int e = c0 + tid * 4; e + 4 <= c1; e += 4096) {
        int4 d4 = *(const int4*)(dst + e);
        atomicAdd(&lhist[d4.x >> BSH2], 1);
        atomicAdd(&lhist[d4.y >> BSH2], 1);
        atomicAdd(&lhist[d4.z >> BSH2], 1);
        atomicAdd(&lhist[d4.w >> BSH2], 1);
    }
    int tail = c0 + ((c1 - c0) & ~3);
    for (int e = tail + tid; e < c1; e += 1024)
        atomicAdd(&lhist[dst[e] >> BSH2], 1);
    __syncthreads();

    // 2: single-wave exclusive scan over 512 counters (2 barriers total)
    if (tid < 64) {
        const int CPL = NB2_MAX / 64;     // 8 counters per lane
        int tmp[CPL];
        int s = 0;
        int base = tid * CPL;
        #pragma unroll
        for (int j = 0; j < CPL; j++) { tmp[j] = s; s += lhist[base + j]; }
        int incl = s;
        #pragma unroll
        for (int o = 1; o < 64; o <<= 1) {
            int t = __shfl_up(incl, o, 64);
            if (tid >= o) incl += t;
        }
        int excl = incl - s;
        #pragma unroll
        for (int j = 0; j < CPL; j++) {
            lbase[base + j] = excl + tmp[j];
            lcur[base + j]  = excl + tmp[j];
        }
    }
    __syncthreads();

    // 3: place chunk into LDS sorted by bucket
    for (int e = c0 + tid * 4; e + 4 <= c1; e += 4096) {
        int4 d4 = *(const int4*)(dst + e);
        int4 s4 = *(const int4*)(src + e);
        int k, pos;
        k = d4.x >> BSH2; pos = atomicAdd(&lcur[k], 1);
        staged[pos] = s4.x | ((d4.x & (NPB - 1)) << 20);
        k = d4.y >> BSH2; pos = atomicAdd(&lcur[k], 1);
        staged[pos] = s4.y | ((d4.y & (NPB - 1)) << 20);
        k = d4.z >> BSH2; pos = atomicAdd(&lcur[k], 1);
        staged[pos] = s4.z | ((d4.z & (NPB - 1)) << 20);
        k = d4.w >> BSH2; pos = atomicAdd(&lcur[k], 1);
        staged[pos] = s4.w | ((d4.w & (NPB - 1)) << 20);
    }
    for (int e = tail + tid; e < c1; e += 1024) {
        int d = dst[e];
        int k = d >> BSH2;
        int pos = atomicAdd(&lcur[k], 1);
        staged[pos] = src[e] | ((d & (NPB - 1)) << 20);
    }
    __syncthreads();

    // 4: parallel reservations
    if (tid < NB2_MAX && tid < NB2) {
        int c = lhist[tid];
        gbase[tid] = c ? atomicAdd(&gcur[tid << 4], (c + 15) & ~15) : 0;
    }
    __syncthreads();

    // 5: flush — 64 groups of 16 lanes stream full 64B lines
    int grp = tid >> 4, sub = tid & 15;
    for (int k = grp; k < NB2; k += 64) {
        int c = lhist[k];
        if (!c) continue;
        int c16 = (c + 15) & ~15;
        int g = gbase[k], base = lbase[k];
        for (int i = sub; i < c16; i += 16)
            packed[g + i] = (i < c) ? staged[base + i] : -1;
    }
}

// ---------------- build: per-bucket CSR + norms + fused fp16 convert ----------------
// Block b: builds per-node CSR for bucket b, computes norm/norm2, then converts
// its own 256 nodes' features to the quarter-major fp16 table [4][N][16]
// (fq[q][node][16] = half(norm[node]*feat[node][q*16+..])) using in-LDS degrees.
__global__ __launch_bounds__(1024) void bucket_csr(const int* __restrict__ packed,
                                                   const int* __restrict__ gcur,
                                                   int2* __restrict__ rbc,
                                                   float* __restrict__ norm,
                                                   float* __restrict__ norm2,
                                                   int* __restrict__ csr,
                                                   const float4* __restrict__ feat,
                                                   uint2* __restrict__ fq,
                                                   int N, int NB2) {
    __shared__ int cnt[NPB];
    __shared__ int loc[NPB];
    int b = blockIdx.x;
    int tid = threadIdx.x;
    if (tid < NPB) cnt[tid] = 0;
    __syncthreads();

    int rbeg = b * CAPP;
    int rend = gcur[b << 4];
    // sweep 1: per-node counts (int4)
    for (int e = rbeg + tid * 4; e + 4 <= rend; e += 4096) {
        int4 p4 = *(const int4*)(packed + e);
        if (p4.x != -1) atomicAdd(&cnt[(p4.x >> 20) & (NPB - 1)], 1);
        if (p4.y != -1) atomicAdd(&cnt[(p4.y >> 20) & (NPB - 1)], 1);
        if (p4.z != -1) atomicAdd(&cnt[(p4.z >> 20) & (NPB - 1)], 1);
        if (p4.w != -1) atomicAdd(&cnt[(p4.w >> 20) & (NPB - 1)], 1);
    }
    __syncthreads();
    // single-wave exclusive scan over 256 counters -> loc
    if (tid < 64) {
        int tmp[4];
        int s = 0;
        int base = tid * 4;
        #pragma unroll
        for (int j = 0; j < 4; j++) { tmp[j] = s; s += cnt[base + j]; }
        int incl = s;
        #pragma unroll
        for (int o = 1; o < 64; o <<= 1) {
            int t = __shfl_up(incl, o, 64);
            if (tid >= o) incl += t;
        }
        int excl = incl - s;
        #pragma unroll
        for (int j = 0; j < 4; j++) loc[base + j] = excl + tmp[j];
    }
    __syncthreads();

    // per-node outputs
    int cbase = b * CAP2;
    if (tid < NPB) {
        int node = (b << BSH2) + tid;
        if (node < N) {
            int v = cnt[tid];
            int ep = loc[tid];
            rbc[node] = make_int2(cbase + ep, v);
            float df = (float)v; df = df < 1.0f ? 1.0f : df;
            float r = rsqrtf(df);
            norm[node] = r;
            norm2[node] = r * r;
        }
    }
    __syncthreads();
    // sweep 2: place compacted csr (loc doubles as placement cursor)
    for (int e = rbeg + tid * 4; e + 4 <= rend; e += 4096) {
        int4 p4 = *(const int4*)(packed + e);
        int l, pos;
        if (p4.x != -1) { l = (p4.x >> 20) & (NPB - 1); pos = atomicAdd(&loc[l], 1); csr[cbase + pos] = p4.x & 0xFFFFF; }
        if (p4.y != -1) { l = (p4.y >> 20) & (NPB - 1); pos = atomicAdd(&loc[l], 1); csr[cbase + pos] = p4.y & 0xFFFFF; }
        if (p4.z != -1) { l = (p4.z >> 20) & (NPB - 1); pos = atomicAdd(&loc[l], 1); csr[cbase + pos] = p4.z & 0xFFFFF; }
        if (p4.w != -1) { l = (p4.w >> 20) & (NPB - 1); pos = atomicAdd(&loc[l], 1); csr[cbase + pos] = p4.w & 0xFFFFF; }
    }

    // fused feat -> fp16 quarter-major conversion (independent of sweep 2;
    // cnt[] is stable since sweep-1 barrier). 256 nodes x 16 float4 = 4096 items.
    #pragma unroll
    for (int it = 0; it < 4; it++) {
        int item = tid + it * 1024;
        int l = item >> 4;
        int node = (b << BSH2) + l;
        if (node < N) {
            int t = item & 15;
            int q = t >> 2, j = t & 3;
            float4 v = feat[(long)node * 16 + t];
            float df = (float)cnt[l]; df = df < 1.0f ? 1.0f : df;
            float r = rsqrtf(df);
            __half2 a = __floats2half2_rn(v.x * r, v.y * r);
            __half2 bb = __floats2half2_rn(v.z * r, v.w * r);
            uint2 u;
            u.x = *(unsigned int*)&a;
            u.y = *(unsigned int*)&bb;
            fq[(long)q * N * 4 + (long)node * 4 + j] = u;
        }
    }
}

// ---------------- gather: XCD-pinned quarter slices ----------------
// Table xq is quarter-major [4][N][16] halves (3.2 MB/quarter). Spatial pinning:
// xcd = blockIdx.x & 7 (HW round-robins consecutive blocks across the 8 XCDs),
// quarter q = xcd & 3, node-chunk = (bid>>3)*2 + (xcd>>2). Each XCD's L2 only
// ever touches ONE quarter slice -> no temporal-overlap thrash (R3's failure).
// csr reads / output stores are non-temporal so streams don't evict the slice.
// 128 nodes per 256-thread block, one node per 2-lane group; 8-wide inner issue.
// Correctness does not depend on the XCD mapping (perf heuristic only).
template <bool OUTHALF>
__global__ __launch_bounds__(256) void gather_pull(const __half* __restrict__ xq,
                                                   const int2* __restrict__ rbc,
                                                   const int* __restrict__ csr,
                                                   const float* __restrict__ post,
                                                   void* __restrict__ outv,
                                                   int N) {
    int bid = blockIdx.x;
    int xcd = bid & 7;
    int q = xcd & 3;
    int chunk = ((bid >> 3) << 1) + (xcd >> 2);
    int grp = threadIdx.x >> 1;
    int sub = threadIdx.x & 1;
    int w = chunk * 128 + grp;
    if (w >= N) return;
    int2 bc = rbc[w];
    int beg = bc.x, end = bc.x + bc.y;
    const uint4* x16 = ((const uint4*)xq) + (long)q * N * 2;   // quarter row = 2 uint4

    float a0 = 0.f, a1 = 0.f, a2 = 0.f, a3 = 0.f;
    float a4 = 0.f, a5 = 0.f, a6 = 0.f, a7 = 0.f;

#define ACC8(u, m) { float2 f_; \
    f_ = __half22float2(*(const __half2*)&(u).x); a0 += f_.x * (m); a1 += f_.y * (m); \
    f_ = __half22float2(*(const __half2*)&(u).y); a2 += f_.x * (m); a3 += f_.y * (m); \
    f_ = __half22float2(*(const __half2*)&(u).z); a4 += f_.x * (m); a5 += f_.y * (m); \
    f_ = __half22float2(*(const __half2*)&(u).w); a6 += f_.x * (m); a7 += f_.y * (m); }

    int e = beg;
    // main: 8 edges per iteration, all loads issued up front
    for (; e + 8 <= end; e += 8) {
        int s0 = __builtin_nontemporal_load(csr + e + 0);
        int s1 = __builtin_nontemporal_load(csr + e + 1);
        int s2 = __builtin_nontemporal_load(csr + e + 2);
        int s3 = __builtin_nontemporal_load(csr + e + 3);
        int s4 = __builtin_nontemporal_load(csr + e + 4);
        int s5 = __builtin_nontemporal_load(csr + e + 5);
        int s6 = __builtin_nontemporal_load(csr + e + 6);
        int s7 = __builtin_nontemporal_load(csr + e + 7);
        uint4 u0 = x16[s0 * 2 + sub];
        uint4 u1 = x16[s1 * 2 + sub];
        uint4 u2 = x16[s2 * 2 + sub];
        uint4 u3 = x16[s3 * 2 + sub];
        uint4 u4 = x16[s4 * 2 + sub];
        uint4 u5 = x16[s5 * 2 + sub];
        uint4 u6 = x16[s6 * 2 + sub];
        uint4 u7 = x16[s7 * 2 + sub];
        ACC8(u0, 1.f) ACC8(u1, 1.f) ACC8(u2, 1.f) ACC8(u3, 1.f)
        ACC8(u4, 1.f) ACC8(u5, 1.f) ACC8(u6, 1.f) ACC8(u7, 1.f)
    }
    // tail: one masked 8-wide pass (indices clamped into [beg, end))
    if (e < end) {
        int i1 = e + 1, i2 = e + 2, i3 = e + 3, i4 = e + 4, i5 = e + 5, i6 = e + 6, i7 = e + 7;
        float m1 = (i1 < end) ? 1.f : 0.f; if (i1 >= end) i1 = end - 1;
        float m2 = (i2 < end) ? 1.f : 0.f; if (i2 >= end) i2 = end - 1;
        float m3 = (i3 < end) ? 1.f : 0.f; if (i3 >= end) i3 = end - 1;
        float m4 = (i4 < end) ? 1.f : 0.f; if (i4 >= end) i4 = end - 1;
        float m5 = (i5 < end) ? 1.f : 0.f; if (i5 >= end) i5 = end - 1;
        float m6 = (i6 < end) ? 1.f : 0.f; if (i6 >= end) i6 = end - 1;
        float m7 = (i7 < end) ? 1.f : 0.f; if (i7 >= end) i7 = end - 1;
        int s0 = __builtin_nontemporal_load(csr + e);
        int s1 = __builtin_nontemporal_load(csr + i1);
        int s2 = __builtin_nontemporal_load(csr + i2);
        int s3 = __builtin_nontemporal_load(csr + i3);
        int s4 = __builtin_nontemporal_load(csr + i4);
        int s5 = __builtin_nontemporal_load(csr + i5);
        int s6 = __builtin_nontemporal_load(csr + i6);
        int s7 = __builtin_nontemporal_load(csr + i7);
        uint4 u0 = x16[s0 * 2 + sub];
        uint4 u1 = x16[s1 * 2 + sub];
        uint4 u2 = x16[s2 * 2 + sub];
        uint4 u3 = x16[s3 * 2 + sub];
        uint4 u4 = x16[s4 * 2 + sub];
        uint4 u5 = x16[s5 * 2 + sub];
        uint4 u6 = x16[s6 * 2 + sub];
        uint4 u7 = x16[s7 * 2 + sub];
        ACC8(u0, 1.f) ACC8(u1, m1) ACC8(u2, m2) ACC8(u3, m3)
        ACC8(u4, m4)  ACC8(u5, m5) ACC8(u6, m6) ACC8(u7, m7)
    }
#undef ACC8

    float pn = post[w];
    a0 *= pn; a1 *= pn; a2 *= pn; a3 *= pn;
    a4 *= pn; a5 *= pn; a6 *= pn; a7 *= pn;
    if (OUTHALF) {
        __half2 h0 = __floats2half2_rn(a0, a1);
        __half2 h1 = __floats2half2_rn(a2, a3);
        __half2 h2 = __floats2half2_rn(a4, a5);
        __half2 h3 = __floats2half2_rn(a6, a7);
        uint32x4 u;
        u.x = *(unsigned int*)&h0;
        u.y = *(unsigned int*)&h1;
        u.z = *(unsigned int*)&h2;
        u.w = *(unsigned int*)&h3;
        __builtin_nontemporal_store(u, ((uint32x4*)outv) + (long)q * N * 2 + (long)w * 2 + sub);
    } else {
        f32x4 r0; r0.x = a0; r0.y = a1; r0.z = a2; r0.w = a3;
        f32x4 r1; r1.x = a4; r1.y = a5; r1.z = a6; r1.w = a7;
        __builtin_nontemporal_store(r0, ((f32x4*)outv) + (long)w * 16 + q * 4 + sub * 2);
        __builtin_nontemporal_store(r1, ((f32x4*)outv) + (long)w * 16 + q * 4 + sub * 2 + 1);
    }
}

// ---------------- fallback (atomic push, pure fp32) ----------------

__global__ void deg_kernel_f(const int* __restrict__ dst, float* __restrict__ deg, int E) {
    int e = blockIdx.x * blockDim.x + threadIdx.x;
    if (e < E) unsafeAtomicAdd(&deg[dst[e]], 1.0f);
}

__global__ void norm_kernel_f(float* __restrict__ deg_norm, float* __restrict__ norm2, int N) {
    int i = blockIdx.x * blockDim.x + threadIdx.x;
    if (i < N) {
        float d = deg_norm[i];
        d = d < 1.0f ? 1.0f : d;
        float r = rsqrtf(d);
        deg_norm[i] = r;
        norm2[i] = r * r;
    }
}

__global__ void scatter_kernel(const float* __restrict__ x,
                               const float* __restrict__ scale,
                               const int* __restrict__ src,
                               const int* __restrict__ dst,
                               float* __restrict__ out, int E) {
    long idx = (long)blockIdx.x * blockDim.x + threadIdx.x;
    int e = (int)(idx >> 6);
    int lane = (int)(idx & 63);
    if (e < E) {
        int s = src[e];
        int d0 = dst[e];
        float v = x[(long)s * D + lane] * scale[s];
        unsafeAtomicAdd(&out[(long)d0 * D + lane], v);
    }
}

__global__ void scale_kernel(float* __restrict__ out, const float* __restrict__ norm, long n) {
    long i = (long)blockIdx.x * blockDim.x + threadIdx.x;
    if (i < n) out[i] *= norm[i >> 6];
}

// ---------------- launch ----------------

extern "C" void kernel_launch(void* const* d_in, const int* in_sizes, int n_in,
                              void* d_out, int out_size, void* d_ws, size_t ws_size,
                              hipStream_t stream) {
    const float* feat = (const float*)d_in[0];
    const int*   src  = (const int*)d_in[1];
    const int*   dst  = (const int*)d_in[2];
    float* out = (float*)d_out;

    const int N = in_sizes[0] / D;   // 100000
    const int E = in_sizes[1];       // 1200000
    const long ND = (long)N * D;
    const int NB2 = (N + NPB - 1) >> BSH2;   // 256-node buckets

    // ws layout (4B elems):
    //   gcur[NB2_MAX*16] | rbc[2N] (int2) | norm[N] | norm2[N] |
    //   csr[NB2*CAP2] | feat16[ND/2] | buf1h[max(ND/2, NB2*CAPP)]
    //   (packed regions alias buf1h -- dead before gather1 writes buf1h)
    long o_gcur = 0;
    long o_rbc  = o_gcur + NB2_MAX * 16;      // even -> int2 aligned
    long o_norm = o_rbc + 2L * N;
    long o_norm2 = o_norm + N;
    long o_csr  = (o_norm2 + N + 3) & ~3L;
    long o_f16  = (o_csr + (long)NB2 * CAP2 + 3) & ~3L;
    long o_buf1 = (o_f16 + ND / 2 + 3) & ~3L;
    long pk_len = (long)NB2 * CAPP;
    long buf1_len = (ND / 2 > pk_len) ? ND / 2 : pk_len;
    size_t need = (size_t)(o_buf1 + buf1_len) * 4;

    if (ws_size >= need && N <= (1 << 20) && NB2 <= NB2_MAX) {
        int*   bi = (int*)d_ws;
        float* bf = (float*)d_ws;
        int* gcur    = bi + o_gcur;
        int2* rbc    = (int2*)(bi + o_rbc);
        float* norm  = bf + o_norm;
        float* norm2 = bf + o_norm2;
        int* csr     = bi + o_csr;
        __half* feat16 = (__half*)(bi + o_f16);   // quarter-major [4][N][16]
        __half* buf1h  = (__half*)(bi + o_buf1);  // quarter-major [4][N][16]
        int* packed  = bi + o_buf1;

        int pblocks = (E + PCHUNK - 1) / PCHUNK;

        init_cursors<<<(NB2 + 255) / 256, 256, 0, stream>>>(gcur, NB2);
        partition_direct<<<pblocks, 1024, 0, stream>>>(src, dst, gcur, packed, E, NB2);
        // CSR + norms + fused fp16 quarter-major conversion
        bucket_csr<<<NB2, 1024, 0, stream>>>(packed, gcur, rbc, norm, norm2, csr,
                                             (const float4*)feat, (uint2*)feat16, N, NB2);

        int NC = (N + 127) / 128;        // 128-node chunks
        int B8 = (NC + 1) / 2;           // chunk pairs (split across XCD pair)
        int grid = B8 * 8;
        // hop 1: buf1h[q] = half( norm2 ⊙ S(feat16[q]) ), XCD-pinned quarters
        gather_pull<true><<<grid, 256, 0, stream>>>(feat16, rbc, csr, norm2, buf1h, N);
        // hop 2: out = norm ⊙ S(buf1h)   (fp32 row-major)
        gather_pull<false><<<grid, 256, 0, stream>>>(buf1h, rbc, csr, norm, out, N);
    } else {
        // fallback: atomic push mode (fp32, needs only 2N+ND floats)
        float* norm  = (float*)d_ws;
        float* norm2 = norm + N;
        float* buf1  = norm2 + N;

        long nz = 2L * N + ND;
        zero_f32<<<(int)((nz + 255) / 256), 256, 0, stream>>>((float*)d_ws, nz);
        zero_f32<<<(int)((ND + 255) / 256), 256, 0, stream>>>(out, ND);
        deg_kernel_f<<<(E + 255) / 256, 256, 0, stream>>>(dst, norm, E);
        norm_kernel_f<<<(N + 255) / 256, 256, 0, stream>>>(norm, norm2, N);
        long work = (long)E * D;
        int blocks = (int)((work + 255) / 256);
        scatter_kernel<<<blocks, 256, 0, stream>>>(feat, norm, src, dst, buf1, E);
        scatter_kernel<<<blocks, 256, 0, stream>>>(buf1, norm2, src, dst, out, E);
        scale_kernel<<<(int)((ND + 255) / 256), 256, 0, stream>>>(out, norm, ND);
    }
}

// Round 7
// 170.993 us; speedup vs baseline: 1.2145x; 1.2145x over previous
//
#include <hip/hip_runtime.h>
#include <hip/hip_fp16.h>

#define D 64
#define BSH2 8                   // 256 nodes per coarse bucket
#define NPB 256                  // nodes per bucket
#define NB2_MAX 512              // max buckets (N <= 131072)
#define PCHUNK 4096              // edges per partition block
#define CAPP 6144                // packed region capacity per bucket (incl. pad, x16)
#define CAP2 4096                // csr region capacity per bucket (real edges)

// clang-native vector types: __builtin_nontemporal_store requires ext_vector_type,
// NOT the HIP_vector_type classes (uint4/float4).
typedef float f32x4 __attribute__((ext_vector_type(4)));

// ---------------- utility ----------------

__global__ void zero_f32(float* __restrict__ p, long n) {
    long i = (long)blockIdx.x * blockDim.x + threadIdx.x;
    long stride = (long)gridDim.x * blockDim.x;
    for (; i < n; i += stride) p[i] = 0.0f;
}

__global__ void init_cursors(int* __restrict__ gcur, int NB2) {
    int i = blockIdx.x * blockDim.x + threadIdx.x;
    if (i < NB2) gcur[i << 4] = i * CAPP;
}

// ---------------- build: single-pass partition (1024 threads) ----------------
__global__ __launch_bounds__(1024) void partition_direct(const int* __restrict__ src,
                                                         const int* __restrict__ dst,
                                                         int* __restrict__ gcur,  // stride 16
                                                         int* __restrict__ packed,
                                                         int E, int NB2) {
    __shared__ int staged[PCHUNK];     // 16 KB sorted chunk
    __shared__ int lhist[NB2_MAX];
    __shared__ int lbase[NB2_MAX];
    __shared__ int lcur[NB2_MAX];
    __shared__ int gbase[NB2_MAX];
    int tid = threadIdx.x;
    int c0 = blockIdx.x * PCHUNK;
    int c1 = c0 + PCHUNK; if (c1 > E) c1 = E;

    if (tid < NB2_MAX) lhist[tid] = 0;
    __syncthreads();

    // 1: histogram
    for (int e = c0 + tid * 4; e + 4 <= c1; e += 4096) {
        int4 d4 = *(const int4*)(dst + e);
        atomicAdd(&lhist[d4.x >> BSH2], 1);
        atomicAdd(&lhist[d4.y >> BSH2], 1);
        atomicAdd(&lhist[d4.z >> BSH2], 1);
        atomicAdd(&lhist[d4.w >> BSH2], 1);
    }
    int tail = c0 + ((c1 - c0) & ~3);
    for (int e = tail + tid; e < c1; e += 1024)
        atomicAdd(&lhist[dst[e] >> BSH2], 1);
    __syncthreads();

    // 2: single-wave exclusive scan over 512 counters
    if (tid < 64) {
        const int CPL = NB2_MAX / 64;     // 8 counters per lane
        int tmp[CPL];
        int s = 0;
        int base = tid * CPL;
        #pragma unroll
        for (int j = 0; j < CPL; j++) { tmp[j] = s; s += lhist[base + j]; }
        int incl = s;
        #pragma unroll
        for (int o = 1; o < 64; o <<= 1) {
            int t = __shfl_up(incl, o, 64);
            if (tid >= o) incl += t;
        }
        int excl = incl - s;
        #pragma unroll
        for (int j = 0; j < CPL; j++) {
            lbase[base + j] = excl + tmp[j];
            lcur[base + j]  = excl + tmp[j];
        }
    }
    __syncthreads();

    // 3: place chunk into LDS sorted by bucket
    for (int e = c0 + tid * 4; e + 4 <= c1; e += 4096) {
        int4 d4 = *(const int4*)(dst + e);
        int4 s4 = *(const int4*)(src + e);
        int k, pos;
        k = d4.x >> BSH2; pos = atomicAdd(&lcur[k], 1);
        staged[pos] = s4.x | ((d4.x & (NPB - 1)) << 20);
        k = d4.y >> BSH2; pos = atomicAdd(&lcur[k], 1);
        staged[pos] = s4.y | ((d4.y & (NPB - 1)) << 20);
        k = d4.z >> BSH2; pos = atomicAdd(&lcur[k], 1);
        staged[pos] = s4.z | ((d4.z & (NPB - 1)) << 20);
        k = d4.w >> BSH2; pos = atomicAdd(&lcur[k], 1);
        staged[pos] = s4.w | ((d4.w & (NPB - 1)) << 20);
    }
    for (int e = tail + tid; e < c1; e += 1024) {
        int d = dst[e];
        int k = d >> BSH2;
        int pos = atomicAdd(&lcur[k], 1);
        staged[pos] = src[e] | ((d & (NPB - 1)) << 20);
    }
    __syncthreads();

    // 4: parallel reservations
    if (tid < NB2_MAX && tid < NB2) {
        int c = lhist[tid];
        gbase[tid] = c ? atomicAdd(&gcur[tid << 4], (c + 15) & ~15) : 0;
    }
    __syncthreads();

    // 5: flush — 64 groups of 16 lanes stream full 64B lines
    int grp = tid >> 4, sub = tid & 15;
    for (int k = grp; k < NB2; k += 64) {
        int c = lhist[k];
        if (!c) continue;
        int c16 = (c + 15) & ~15;
        int g = gbase[k], base = lbase[k];
        for (int i = sub; i < c16; i += 16)
            packed[g + i] = (i < c) ? staged[base + i] : -1;
    }
}

// ---------------- build: per-bucket CSR + norms + fused fp16 convert ----------------
// Block b: builds per-node CSR for bucket b, computes norm/norm2, then converts
// its own 256 nodes' features to ROW-MAJOR fp16 [N][64] using in-LDS degrees.
__global__ __launch_bounds__(1024) void bucket_csr(const int* __restrict__ packed,
                                                   const int* __restrict__ gcur,
                                                   int2* __restrict__ rbc,
                                                   float* __restrict__ norm,
                                                   float* __restrict__ norm2,
                                                   int* __restrict__ csr,
                                                   const float4* __restrict__ feat,
                                                   uint2* __restrict__ fq,
                                                   int N, int NB2) {
    __shared__ int cnt[NPB];
    __shared__ int loc[NPB];
    int b = blockIdx.x;
    int tid = threadIdx.x;
    if (tid < NPB) cnt[tid] = 0;
    __syncthreads();

    int rbeg = b * CAPP;
    int rend = gcur[b << 4];
    // sweep 1: per-node counts (int4)
    for (int e = rbeg + tid * 4; e + 4 <= rend; e += 4096) {
        int4 p4 = *(const int4*)(packed + e);
        if (p4.x != -1) atomicAdd(&cnt[(p4.x >> 20) & (NPB - 1)], 1);
        if (p4.y != -1) atomicAdd(&cnt[(p4.y >> 20) & (NPB - 1)], 1);
        if (p4.z != -1) atomicAdd(&cnt[(p4.z >> 20) & (NPB - 1)], 1);
        if (p4.w != -1) atomicAdd(&cnt[(p4.w >> 20) & (NPB - 1)], 1);
    }
    __syncthreads();
    // single-wave exclusive scan over 256 counters -> loc
    if (tid < 64) {
        int tmp[4];
        int s = 0;
        int base = tid * 4;
        #pragma unroll
        for (int j = 0; j < 4; j++) { tmp[j] = s; s += cnt[base + j]; }
        int incl = s;
        #pragma unroll
        for (int o = 1; o < 64; o <<= 1) {
            int t = __shfl_up(incl, o, 64);
            if (tid >= o) incl += t;
        }
        int excl = incl - s;
        #pragma unroll
        for (int j = 0; j < 4; j++) loc[base + j] = excl + tmp[j];
    }
    __syncthreads();

    // per-node outputs
    int cbase = b * CAP2;
    if (tid < NPB) {
        int node = (b << BSH2) + tid;
        if (node < N) {
            int v = cnt[tid];
            int ep = loc[tid];
            rbc[node] = make_int2(cbase + ep, v);
            float df = (float)v; df = df < 1.0f ? 1.0f : df;
            float r = rsqrtf(df);
            norm[node] = r;
            norm2[node] = r * r;
        }
    }
    __syncthreads();
    // sweep 2: place compacted csr (loc doubles as placement cursor)
    for (int e = rbeg + tid * 4; e + 4 <= rend; e += 4096) {
        int4 p4 = *(const int4*)(packed + e);
        int l, pos;
        if (p4.x != -1) { l = (p4.x >> 20) & (NPB - 1); pos = atomicAdd(&loc[l], 1); csr[cbase + pos] = p4.x & 0xFFFFF; }
        if (p4.y != -1) { l = (p4.y >> 20) & (NPB - 1); pos = atomicAdd(&loc[l], 1); csr[cbase + pos] = p4.y & 0xFFFFF; }
        if (p4.z != -1) { l = (p4.z >> 20) & (NPB - 1); pos = atomicAdd(&loc[l], 1); csr[cbase + pos] = p4.z & 0xFFFFF; }
        if (p4.w != -1) { l = (p4.w >> 20) & (NPB - 1); pos = atomicAdd(&loc[l], 1); csr[cbase + pos] = p4.w & 0xFFFFF; }
    }

    // fused feat -> fp16 ROW-MAJOR conversion (cnt[] stable since sweep-1 barrier).
    // 256 nodes x 16 uint2 (8B) = 4096 items; row = 64 half = 16 uint2.
    #pragma unroll
    for (int it = 0; it < 4; it++) {
        int item = tid + it * 1024;
        int l = item >> 4;
        int node = (b << BSH2) + l;
        if (node < N) {
            int t = item & 15;
            float4 v = feat[(long)node * 16 + t];
            float df = (float)cnt[l]; df = df < 1.0f ? 1.0f : df;
            float r = rsqrtf(df);
            __half2 a = __floats2half2_rn(v.x * r, v.y * r);
            __half2 bb = __floats2half2_rn(v.z * r, v.w * r);
            uint2 u;
            u.x = *(unsigned int*)&a;
            u.y = *(unsigned int*)&bb;
            fq[(long)node * 16 + t] = u;
        }
    }
}

// ---------------- gather: row-major fp16, one node per wave, burst issue ----------------
// R0's winning shape (128 B rows, 8-lane groups -> 8 edges in parallel per wave
// instruction, TA-friendly coalescing) + the fix for its multi-round issue:
// deg is WAVE-UNIFORM (one node per wave), so branch on deg and issue ALL of the
// node's csr+row loads in one unrolled burst before any use -> one latency round
// for deg<=32 (~99% of nodes at mean deg 12). Masked slots clamp to edge 0
// (valid; dup lines are L2-warm). No LDS, no barriers.
template <int NS>
__device__ __forceinline__ void burst(const uint4* __restrict__ x16,
                                      const int* __restrict__ csr,
                                      int beg, int deg, int off,
                                      int g, int sub, float* a) {
    int e[NS]; float m[NS]; int s[NS]; uint4 u[NS];
    #pragma unroll
    for (int i = 0; i < NS; i++) {
        int idx = g + off + 8 * i;
        bool v = idx < deg;
        e[i] = v ? beg + idx : beg;
        m[i] = v ? 1.f : 0.f;
    }
    #pragma unroll
    for (int i = 0; i < NS; i++) s[i] = csr[e[i]];
    #pragma unroll
    for (int i = 0; i < NS; i++) u[i] = x16[s[i] * 8 + sub];
    #pragma unroll
    for (int i = 0; i < NS; i++) {
        float2 f;
        f = __half22float2(*(const __half2*)&u[i].x); a[0] += f.x * m[i]; a[1] += f.y * m[i];
        f = __half22float2(*(const __half2*)&u[i].y); a[2] += f.x * m[i]; a[3] += f.y * m[i];
        f = __half22float2(*(const __half2*)&u[i].z); a[4] += f.x * m[i]; a[5] += f.y * m[i];
        f = __half22float2(*(const __half2*)&u[i].w); a[6] += f.x * m[i]; a[7] += f.y * m[i];
    }
}

template <bool OUTHALF>
__global__ __launch_bounds__(256) void gather_row(const __half* __restrict__ x,
                                                  const int2* __restrict__ rbc,
                                                  const int* __restrict__ csr,
                                                  const float* __restrict__ post,
                                                  void* __restrict__ outv, int N) {
    int w = blockIdx.x * 4 + (threadIdx.x >> 6);
    if (w >= N) return;
    int lane = threadIdx.x & 63;
    int g = lane >> 3;        // 8 edge-groups
    int sub = lane & 7;       // 16 B slice within 128 B row
    int2 bc = rbc[w];
    int beg = bc.x, deg = bc.y;
    const uint4* x16 = (const uint4*)x;
    float pn = post[w];
    float a[8];
    #pragma unroll
    for (int i = 0; i < 8; i++) a[i] = 0.f;

    if (deg > 0) {
        if (deg <= 8) {
            burst<1>(x16, csr, beg, deg, 0, g, sub, a);
        } else if (deg <= 16) {
            burst<2>(x16, csr, beg, deg, 0, g, sub, a);
        } else if (deg <= 32) {
            burst<4>(x16, csr, beg, deg, 0, g, sub, a);
        } else {
            for (int off = 0; off < deg; off += 32)
                burst<4>(x16, csr, beg, deg, off, g, sub, a);
        }
    }

    // reduce across the 8 groups (lane bits 3..5); sub lanes hold distinct features
    #pragma unroll
    for (int i = 0; i < 8; i++) {
        a[i] += __shfl_xor(a[i], 8, 64);
        a[i] += __shfl_xor(a[i], 16, 64);
        a[i] += __shfl_xor(a[i], 32, 64);
    }
    if (g == 0) {
        #pragma unroll
        for (int i = 0; i < 8; i++) a[i] *= pn;
        if (OUTHALF) {
            __half2 h0 = __floats2half2_rn(a[0], a[1]);
            __half2 h1 = __floats2half2_rn(a[2], a[3]);
            __half2 h2 = __floats2half2_rn(a[4], a[5]);
            __half2 h3 = __floats2half2_rn(a[6], a[7]);
            uint4 u;
            u.x = *(unsigned int*)&h0;
            u.y = *(unsigned int*)&h1;
            u.z = *(unsigned int*)&h2;
            u.w = *(unsigned int*)&h3;
            ((uint4*)outv)[(long)w * 8 + sub] = u;   // re-read by hop 2: keep cached
        } else {
            f32x4 r0; r0.x = a[0]; r0.y = a[1]; r0.z = a[2]; r0.w = a[3];
            f32x4 r1; r1.x = a[4]; r1.y = a[5]; r1.z = a[6]; r1.w = a[7];
            __builtin_nontemporal_store(r0, ((f32x4*)outv) + (long)w * 16 + sub * 2);
            __builtin_nontemporal_store(r1, ((f32x4*)outv) + (long)w * 16 + sub * 2 + 1);
        }
    }
}

// ---------------- fallback (atomic push, pure fp32) ----------------

__global__ void deg_kernel_f(const int* __restrict__ dst, float* __restrict__ deg, int E) {
    int e = blockIdx.x * blockDim.x + threadIdx.x;
    if (e < E) unsafeAtomicAdd(&deg[dst[e]], 1.0f);
}

__global__ void norm_kernel_f(float* __restrict__ deg_norm, float* __restrict__ norm2, int N) {
    int i = blockIdx.x * blockDim.x + threadIdx.x;
    if (i < N) {
        float d = deg_norm[i];
        d = d < 1.0f ? 1.0f : d;
        float r = rsqrtf(d);
        deg_norm[i] = r;
        norm2[i] = r * r;
    }
}

__global__ void scatter_kernel(const float* __restrict__ x,
                               const float* __restrict__ scale,
                               const int* __restrict__ src,
                               const int* __restrict__ dst,
                               float* __restrict__ out, int E) {
    long idx = (long)blockIdx.x * blockDim.x + threadIdx.x;
    int e = (int)(idx >> 6);
    int lane = (int)(idx & 63);
    if (e < E) {
        int s = src[e];
        int d0 = dst[e];
        float v = x[(long)s * D + lane] * scale[s];
        unsafeAtomicAdd(&out[(long)d0 * D + lane], v);
    }
}

__global__ void scale_kernel(float* __restrict__ out, const float* __restrict__ norm, long n) {
    long i = (long)blockIdx.x * blockDim.x + threadIdx.x;
    if (i < n) out[i] *= norm[i >> 6];
}

// ---------------- launch ----------------

extern "C" void kernel_launch(void* const* d_in, const int* in_sizes, int n_in,
                              void* d_out, int out_size, void* d_ws, size_t ws_size,
                              hipStream_t stream) {
    const float* feat = (const float*)d_in[0];
    const int*   src  = (const int*)d_in[1];
    const int*   dst  = (const int*)d_in[2];
    float* out = (float*)d_out;

    const int N = in_sizes[0] / D;   // 100000
    const int E = in_sizes[1];       // 1200000
    const long ND = (long)N * D;
    const int NB2 = (N + NPB - 1) >> BSH2;   // 256-node buckets

    // ws layout (4B elems):
    //   gcur[NB2_MAX*16] | rbc[2N] (int2) | norm[N] | norm2[N] |
    //   csr[NB2*CAP2] | feat16[ND/2] | buf1h[max(ND/2, NB2*CAPP)]
    //   (packed regions alias buf1h -- dead before gather1 writes buf1h)
    long o_gcur = 0;
    long o_rbc  = o_gcur + NB2_MAX * 16;      // even -> int2 aligned
    long o_norm = o_rbc + 2L * N;
    long o_norm2 = o_norm + N;
    long o_csr  = (o_norm2 + N + 3) & ~3L;
    long o_f16  = (o_csr + (long)NB2 * CAP2 + 3) & ~3L;
    long o_buf1 = (o_f16 + ND / 2 + 3) & ~3L;
    long pk_len = (long)NB2 * CAPP;
    long buf1_len = (ND / 2 > pk_len) ? ND / 2 : pk_len;
    size_t need = (size_t)(o_buf1 + buf1_len) * 4;

    if (ws_size >= need && N <= (1 << 20) && NB2 <= NB2_MAX) {
        int*   bi = (int*)d_ws;
        float* bf = (float*)d_ws;
        int* gcur    = bi + o_gcur;
        int2* rbc    = (int2*)(bi + o_rbc);
        float* norm  = bf + o_norm;
        float* norm2 = bf + o_norm2;
        int* csr     = bi + o_csr;
        __half* feat16 = (__half*)(bi + o_f16);   // row-major [N][64] half
        __half* buf1h  = (__half*)(bi + o_buf1);  // row-major [N][64] half
        int* packed  = bi + o_buf1;

        int pblocks = (E + PCHUNK - 1) / PCHUNK;

        init_cursors<<<(NB2 + 255) / 256, 256, 0, stream>>>(gcur, NB2);
        partition_direct<<<pblocks, 1024, 0, stream>>>(src, dst, gcur, packed, E, NB2);
        // CSR + norms + fused row-major fp16 conversion
        bucket_csr<<<NB2, 1024, 0, stream>>>(packed, gcur, rbc, norm, norm2, csr,
                                             (const float4*)feat, (uint2*)feat16, N, NB2);

        int gblocks = (N + 3) / 4;   // one node per wave, 4 waves per block
        // hop 1: buf1h = half( norm2 ⊙ S(feat16) )
        gather_row<true><<<gblocks, 256, 0, stream>>>(feat16, rbc, csr, norm2, buf1h, N);
        // hop 2: out = norm ⊙ S(buf1h)   (fp32 row-major)
        gather_row<false><<<gblocks, 256, 0, stream>>>(buf1h, rbc, csr, norm, out, N);
    } else {
        // fallback: atomic push mode (fp32, needs only 2N+ND floats)
        float* norm  = (float*)d_ws;
        float* norm2 = norm + N;
        float* buf1  = norm2 + N;

        long nz = 2L * N + ND;
        zero_f32<<<(int)((nz + 255) / 256), 256, 0, stream>>>((float*)d_ws, nz);
        zero_f32<<<(int)((ND + 255) / 256), 256, 0, stream>>>(out, ND);
        deg_kernel_f<<<(E + 255) / 256, 256, 0, stream>>>(dst, norm, E);
        norm_kernel_f<<<(N + 255) / 256, 256, 0, stream>>>(norm, norm2, N);
        long work = (long)E * D;
        int blocks = (int)((work + 255) / 256);
        scatter_kernel<<<blocks, 256, 0, stream>>>(feat, norm, src, dst, buf1, E);
        scatter_kernel<<<blocks, 256, 0, stream>>>(buf1, norm2, src, dst, out, E);
        scale_kernel<<<(int)((ND + 255) / 256), 256, 0, stream>>>(out, norm, ND);
    }
}